// Round 6
// baseline (280.586 us; speedup 1.0000x reference)
//
#include <hip/hip_runtime.h>

// out[b,k] = sum_l max_m dot(ctx[b,k,l,:], ent[b,k,m,:])
// ctx = context[:,:,0,:,:], ent = context[:,:,1,:,:]
// BATCH=8 TOP_K=64 MAX_LEN=256 EMB_DIM=768, fp32 in, fp32 out (8x64=512)
//
// R6: R2 structure + DISTANCE-2 B prefetch. Step s commits B(s+1) issued at
//     step s-2 (always arrived -> no vmcnt stall before the barrier) and
//     issues B(s+3) into the freed register set (rb0/rb1 alternate). A stays
//     distance-1 (4 loads, ~1000cy shadow). Barriers drain lgkmcnt only;
//     16 B-loads + A-loads stay in flight across every barrier.

#define MAXLEN 256
#define EMB 768
#define BK 64
#define NSTEP 12
#define LSTRIDE 72  // 64 + 8 pad shorts -> 144B row stride

typedef __attribute__((ext_vector_type(4))) float f32x4;
typedef __attribute__((ext_vector_type(8))) short short8;
typedef __bf16 bf16x8 __attribute__((ext_vector_type(8)));
typedef __bf16 bf16x4 __attribute__((ext_vector_type(4)));

__device__ inline bf16x8 cvt8(float4 a, float4 b) {
  bf16x8 r;
  r[0] = (__bf16)a.x; r[1] = (__bf16)a.y; r[2] = (__bf16)a.z; r[3] = (__bf16)a.w;
  r[4] = (__bf16)b.x; r[5] = (__bf16)b.y; r[6] = (__bf16)b.z; r[7] = (__bf16)b.w;
  return r;
}

__device__ inline uint2 cvt4u(float4 v) {
  union { uint2 u; bf16x4 h; } r;
  r.h[0] = (__bf16)v.x; r.h[1] = (__bf16)v.y;
  r.h[2] = (__bf16)v.z; r.h[3] = (__bf16)v.w;
  return r.u;
}

__global__ __launch_bounds__(512, 2) void som_rowmax_kernel(
    const float* __restrict__ ctx_all, float* __restrict__ out) {
  __shared__ __align__(16) short lsB[2][MAXLEN][LSTRIDE];
  __shared__ float red[8];

  const int t    = threadIdx.x;
  const int w    = t >> 6;      // wave 0..7
  const int lane = t & 63;
  const int qw   = lane >> 4;   // quarter-wave 0..3
  const int lr   = lane & 15;

  const size_t p = blockIdx.x;  // b*64 + k
  const float* ctx = ctx_all + p * (size_t)(2 * MAXLEN * EMB);
  const float* ent = ctx + (size_t)(MAXLEN * EMB);

  // B staging: 8 rounds x (32 rows x 16 lanes x float4) covers 256x64 f32
  const int srow = t >> 4;         // 0..31
  const int scol = (t & 15) * 4;   // f32 col 0,4,...,60
  const float* gB = ent + (size_t)srow * EMB + scol;

  // A fragments: wave w owns sim rows 32w..32w+31 (two 16-row tiles)
  const float* gA0 = ctx + (size_t)(32 * w + lr) * EMB + qw * 8;
  const float* gA1 = ctx + (size_t)(32 * w + 16 + lr) * EMB + qw * 8;

  f32x4 acc[2][16];
  float4 rb0[8], rb1[8];  // two B staging sets (distance-2 pipeline)
  float4 ra[4];           // A(s+1) in flight
  bf16x8 afr[2][2];       // A(s) fragments [tile][kh]

  auto issueB = [&](float4 (&rbc)[8], int s) {
#pragma unroll
    for (int j = 0; j < 8; ++j)
      rbc[j] = *(const float4*)(gB + (size_t)j * (32 * EMB) + s * BK);
  };
  auto commitB = [&](float4 (&rbc)[8], int buf) {
#pragma unroll
    for (int j = 0; j < 8; ++j)
      *(uint2*)&lsB[buf][j * 32 + srow][scol] = cvt4u(rbc[j]);
  };
  auto issueA = [&](int s) {
    ra[0] = *(const float4*)(gA0 + s * BK + 0);
    ra[1] = *(const float4*)(gA0 + s * BK + 4);
    ra[2] = *(const float4*)(gA1 + s * BK + 0);
    ra[3] = *(const float4*)(gA1 + s * BK + 4);
  };
  auto issueA1 = [&](int s) {  // kh=1 halves reuse ra via second pack
    ra[0] = *(const float4*)(gA0 + s * BK + 32);
    ra[1] = *(const float4*)(gA0 + s * BK + 36);
    ra[2] = *(const float4*)(gA1 + s * BK + 32);
    ra[3] = *(const float4*)(gA1 + s * BK + 36);
  };
  auto packA = [&](int kh) {
    afr[0][kh] = cvt8(ra[0], ra[1]);
    afr[1][kh] = cvt8(ra[2], ra[3]);
  };
  auto mfmaStep = [&](int buf) {
#pragma unroll
    for (int kh = 0; kh < 2; ++kh) {
      const int kq = kh * 32 + qw * 8;
#pragma unroll
      for (int mt = 0; mt < 16; ++mt) {
        bf16x8 bfr = __builtin_bit_cast(bf16x8, *(const short8*)&lsB[buf][mt * 16 + lr][kq]);
        acc[0][mt] = __builtin_amdgcn_mfma_f32_16x16x32_bf16(afr[0][kh], bfr, acc[0][mt], 0, 0, 0);
        acc[1][mt] = __builtin_amdgcn_mfma_f32_16x16x32_bf16(afr[1][kh], bfr, acc[1][mt], 0, 0, 0);
      }
    }
  };
  // barrier that does NOT drain vmcnt: global loads stay in flight across it
  auto barrier = [&]() {
    asm volatile("s_waitcnt lgkmcnt(0)" ::: "memory");
    __builtin_amdgcn_sched_barrier(0);
    __builtin_amdgcn_s_barrier();
    __builtin_amdgcn_sched_barrier(0);
  };

  // steady-state step body. Invariant at entry (s>=1): lsB[s&1]=B(s),
  // afr=A(s), rb[s&1] holds B(s+1) (issued at s-2), rb[(s+1)&1] = B(s+2)
  // in flight.
  auto body = [&](int s, float4 (&rbc)[8], bool issueNext) {
    issueA(s + 1);                    // A(s+1) kh0 into flight
    commitB(rbc, (s + 1) & 1);        // B(s+1): issued 2 steps ago, no stall
    if (issueNext) issueB(rbc, s + 3);
    mfmaStep(s & 1);                  // consume B(s), afr=A(s)
    packA(0);                         // waits A(s+1) kh0
    issueA1(s + 1);                   // A(s+1) kh1
    packA(1);                         // waits A(s+1) kh1
    barrier();                        // lgkm only; B/A loads ride across
  };

  // ---- prologue ----
  issueB(rb0, 0);
  issueA(0);
  commitB(rb0, 0);     // waits B(0); A(0) in flight
  issueB(rb0, 1);
#pragma unroll
  for (int ti = 0; ti < 2; ++ti)
#pragma unroll
    for (int mt = 0; mt < 16; ++mt) acc[ti][mt] = (f32x4){0.f, 0.f, 0.f, 0.f};
  packA(0);            // waits A(0) kh0; B(1) in flight
  issueA1(0);
  packA(1);            // waits A(0) kh1
  issueB(rb1, 2);
  barrier();           // B(1)+B(2) = 16 loads in flight across

  // ---- steady state: steps 0..10 (commit B(s+1), compute B(s)) ----
#pragma unroll 1
  for (int ss = 0; ss < 5; ++ss) {
    body(2 * ss + 0, rb0, 2 * ss + 0 < 9);
    body(2 * ss + 1, rb1, 2 * ss + 1 < 9);
  }
  body(10, rb0, false);
  // ---- final step: compute B(11) ----
  mfmaStep(1);

  // ---- epilogue: rowmax over m (256 cols), then sum over rows ----
  // C/D layout (16x16x32): col = lane&15, row = (lane>>4)*4 + reg
  float s = 0.f;
#pragma unroll
  for (int ti = 0; ti < 2; ++ti) {
#pragma unroll
    for (int i = 0; i < 4; ++i) {
      float m = acc[ti][0][i];
#pragma unroll
      for (int mt = 1; mt < 16; ++mt) m = fmaxf(m, acc[ti][mt][i]);
#pragma unroll
      for (int d = 1; d < 16; d <<= 1) m = fmaxf(m, __shfl_xor(m, d, 64));
      s += m;
    }
  }
  s += __shfl_xor(s, 16, 64);
  s += __shfl_xor(s, 32, 64);

  if (lane == 0) red[w] = s;
  __syncthreads();
  if (t == 0) {
    float tot = 0.f;
#pragma unroll
    for (int i = 0; i < 8; ++i) tot += red[i];
    out[p] = tot;
  }
}

extern "C" void kernel_launch(void* const* d_in, const int* in_sizes, int n_in,
                              void* d_out, int out_size, void* d_ws, size_t ws_size,
                              hipStream_t stream) {
  const float* ctx_all = (const float*)d_in[0];
  float* out = (float*)d_out;
  som_rowmax_kernel<<<dim3(512), dim3(512), 0, stream>>>(ctx_all, out);
}

// Round 7
// 219.305 us; speedup vs baseline: 1.2794x; 1.2794x over previous
//
#include <hip/hip_runtime.h>

// out[b,k] = sum_l max_m dot(ctx[b,k,l,:], ent[b,k,m,:])
// ctx = context[:,:,0,:,:], ent = context[:,:,1,:,:]
// BATCH=8 TOP_K=64 MAX_LEN=256 EMB_DIM=768, fp32 in, fp32 out (8x64=512)
//
// R7: clean BK=128 test. 1024 threads / 16 waves, each wave owns ONE 16-row
//     strip -> acc=64 VGPR, so BK=128 staging fits without spills
//     (rb 32 + ra 32 + afr 16 -> ~175 total < 256). B double-buffered in LDS
//     (2 x 256 x 136 shorts = 139KB, 1 block/CU). Every B row read as a
//     512B contiguous DRAM chunk (2 rows per wave instruction). 6 K-steps,
//     lgkm-only barriers, loads in flight across every barrier.

#define MAXLEN 256
#define EMB 768
#define BK 128
#define NSTEP 6
#define LSTRIDE 136  // 128 + 8 pad shorts -> 272B = 17 x 16B granules (1 mod 8)

typedef __attribute__((ext_vector_type(4))) float f32x4;
typedef __attribute__((ext_vector_type(8))) short short8;
typedef __bf16 bf16x8 __attribute__((ext_vector_type(8)));
typedef __bf16 bf16x4 __attribute__((ext_vector_type(4)));

__device__ inline bf16x8 cvt8(float4 a, float4 b) {
  bf16x8 r;
  r[0] = (__bf16)a.x; r[1] = (__bf16)a.y; r[2] = (__bf16)a.z; r[3] = (__bf16)a.w;
  r[4] = (__bf16)b.x; r[5] = (__bf16)b.y; r[6] = (__bf16)b.z; r[7] = (__bf16)b.w;
  return r;
}

__device__ inline uint2 cvt4u(float4 v) {
  union { uint2 u; bf16x4 h; } r;
  r.h[0] = (__bf16)v.x; r.h[1] = (__bf16)v.y;
  r.h[2] = (__bf16)v.z; r.h[3] = (__bf16)v.w;
  return r.u;
}

__global__ __launch_bounds__(1024, 1) void som_rowmax_kernel(
    const float* __restrict__ ctx_all, float* __restrict__ out) {
  __shared__ __align__(16) short lsB[2][MAXLEN][LSTRIDE];
  __shared__ float red[16];

  const int t    = threadIdx.x;
  const int w    = t >> 6;      // wave 0..15
  const int lane = t & 63;
  const int qw   = lane >> 4;   // quarter-wave 0..3
  const int lr   = lane & 15;

  const size_t p = blockIdx.x;  // b*64 + k
  const float* ctx = ctx_all + p * (size_t)(2 * MAXLEN * EMB);
  const float* ent = ctx + (size_t)(MAXLEN * EMB);

  // B staging: 8 rounds x (32 rows x 32 lanes-per-row float4) = 256 x 128 f32.
  // One wave instruction = 2 rows x 512B fully contiguous.
  const int srow = t >> 5;         // 0..31
  const int scol = (t & 31) * 4;   // f32 col 0,4,...,124
  const float* gB = ent + (size_t)srow * EMB + scol;

  // A: wave w owns sim rows 16w..16w+15; lane holds A row 16w+lr
  const float* gA = ctx + (size_t)(16 * w + lr) * EMB + qw * 8;

  f32x4 acc[16];       // 64 VGPR
  float4 rb[8];        // B(s+1) in flight (32 VGPR)
  float4 ra0[4];       // A(s+1) kh01 in flight (16)
  float4 ra1[4];       // A(s+1) kh23 in flight (16)
  bf16x8 afr[4];       // A(s) fragments (16)

  auto issueB = [&](int s) {
#pragma unroll
    for (int j = 0; j < 8; ++j)
      rb[j] = *(const float4*)(gB + (size_t)j * (32 * EMB) + s * BK);
  };
  auto commitB = [&](int buf) {
#pragma unroll
    for (int j = 0; j < 8; ++j)
      *(uint2*)&lsB[buf][j * 32 + srow][scol] = cvt4u(rb[j]);
  };
  auto issueA01 = [&](int s) {
    ra0[0] = *(const float4*)(gA + s * BK + 0);
    ra0[1] = *(const float4*)(gA + s * BK + 4);
    ra0[2] = *(const float4*)(gA + s * BK + 32);
    ra0[3] = *(const float4*)(gA + s * BK + 36);
  };
  auto issueA23 = [&](int s) {
    ra1[0] = *(const float4*)(gA + s * BK + 64);
    ra1[1] = *(const float4*)(gA + s * BK + 68);
    ra1[2] = *(const float4*)(gA + s * BK + 96);
    ra1[3] = *(const float4*)(gA + s * BK + 100);
  };
  auto packA = [&]() {
    afr[0] = cvt8(ra0[0], ra0[1]);
    afr[1] = cvt8(ra0[2], ra0[3]);
    afr[2] = cvt8(ra1[0], ra1[1]);
    afr[3] = cvt8(ra1[2], ra1[3]);
  };
  auto mfmaStep = [&](int buf) {
#pragma unroll
    for (int kh = 0; kh < 4; ++kh) {
      const int kq = kh * 32 + qw * 8;
#pragma unroll
      for (int mt = 0; mt < 16; ++mt) {
        bf16x8 bfr = __builtin_bit_cast(bf16x8, *(const short8*)&lsB[buf][mt * 16 + lr][kq]);
        acc[mt] = __builtin_amdgcn_mfma_f32_16x16x32_bf16(afr[kh], bfr, acc[mt], 0, 0, 0);
      }
    }
  };
  // barrier that does NOT drain vmcnt: global loads stay in flight across it
  auto barrier = [&]() {
    asm volatile("s_waitcnt lgkmcnt(0)" ::: "memory");
    __builtin_amdgcn_sched_barrier(0);
    __builtin_amdgcn_s_barrier();
    __builtin_amdgcn_sched_barrier(0);
  };

  // ---- prologue ----
  issueB(0);
  issueA01(0);
  issueA23(0);
  commitB(0);          // waits rb=B(0); A(0) stays in flight
  issueB(1);
#pragma unroll
  for (int mt = 0; mt < 16; ++mt) acc[mt] = (f32x4){0.f, 0.f, 0.f, 0.f};
  packA();             // waits A(0); B(1) stays in flight
  barrier();

  // ---- steady state: s = 0..NSTEP-2 ----
  for (int s = 0; s < NSTEP - 1; ++s) {
    issueA01(s + 1);
    issueA23(s + 1);
    commitB((s + 1) & 1);       // waits rb=B(s+1) (issued last step); A in flight
    if (s + 2 < NSTEP) issueB(s + 2);
    mfmaStep(s & 1);            // consume B(s) + afr=A(s)
    packA();                    // waits A(s+1); B(s+2) stays in flight
    barrier();                  // lgkm only; B(s+2) rides across
  }
  // ---- final step ----
  mfmaStep((NSTEP - 1) & 1);

  // ---- epilogue: rowmax over m (256 cols), then sum over rows ----
  // C/D layout (16x16x32): col = lane&15, row = (lane>>4)*4 + reg
  float s = 0.f;
#pragma unroll
  for (int i = 0; i < 4; ++i) {
    float m = acc[0][i];
#pragma unroll
    for (int mt = 1; mt < 16; ++mt) m = fmaxf(m, acc[mt][i]);
#pragma unroll
    for (int d = 1; d < 16; d <<= 1) m = fmaxf(m, __shfl_xor(m, d, 64));
    s += m;
  }
  // qw-groups hold disjoint row quartets of this wave's strip
  s += __shfl_xor(s, 16, 64);
  s += __shfl_xor(s, 32, 64);

  if (lane == 0) red[w] = s;
  __syncthreads();
  if (t == 0) {
    float tot = 0.f;
#pragma unroll
    for (int i = 0; i < 16; ++i) tot += red[i];
    out[p] = tot;
  }
}

extern "C" void kernel_launch(void* const* d_in, const int* in_sizes, int n_in,
                              void* d_out, int out_size, void* d_ws, size_t ws_size,
                              hipStream_t stream) {
  const float* ctx_all = (const float*)d_in[0];
  float* out = (float*)d_out;
  som_rowmax_kernel<<<dim3(512), dim3(1024), 0, stream>>>(ctx_all, out);
}

// Round 8
// 152.567 us; speedup vs baseline: 1.8391x; 1.4374x over previous
//
#include <hip/hip_runtime.h>

// out[b,k] = sum_l max_m dot(ctx[b,k,l,:], ent[b,k,m,:])
// ctx = context[:,:,0,:,:], ent = context[:,:,1,:,:]
// BATCH=8 TOP_K=64 MAX_LEN=256 EMB_DIM=768, fp32 in, fp32 out (8x64=512)
//
// R8: exact R2 structure (the 150.6us winner: 8 waves, 2 blocks/CU, BK=64,
//     B double-buffered LDS, A global->reg->frag, lgkm-only barriers with
//     loads in flight across) + NON-TEMPORAL staging loads (nt flag, no L2
//     allocation for the once-streamed 805MB).

#define MAXLEN 256
#define EMB 768
#define BK 64
#define NSTEP 12
#define LSTRIDE 72  // 64 + 8 pad shorts -> 144B row stride

typedef __attribute__((ext_vector_type(4))) float f32x4;
typedef __attribute__((ext_vector_type(8))) short short8;
typedef __bf16 bf16x8 __attribute__((ext_vector_type(8)));

// round-to-nearest-even f32 -> bf16, packed pair (a -> low 16, b -> high 16)
__device__ inline unsigned int pack2bf(float a, float b) {
  unsigned int ua = __builtin_bit_cast(unsigned int, a);
  unsigned int ub = __builtin_bit_cast(unsigned int, b);
  ua = (ua + (0x7fffu + ((ua >> 16) & 1u))) >> 16;
  ub = (ub + (0x7fffu + ((ub >> 16) & 1u))) & 0xffff0000u;
  return ua | ub;
}

__device__ inline uint2 pack4bf(f32x4 v) {
  uint2 r;
  r.x = pack2bf(v[0], v[1]);
  r.y = pack2bf(v[2], v[3]);
  return r;
}

__device__ inline bf16x8 pack8bf(f32x4 a, f32x4 b) {
  union { unsigned int u[4]; bf16x8 v; } r;
  r.u[0] = pack2bf(a[0], a[1]);
  r.u[1] = pack2bf(a[2], a[3]);
  r.u[2] = pack2bf(b[0], b[1]);
  r.u[3] = pack2bf(b[2], b[3]);
  return r.v;
}

__device__ inline f32x4 ntload(const float* p) {
  return __builtin_nontemporal_load((const f32x4*)p);
}

__global__ __launch_bounds__(512, 2) void som_rowmax_kernel(
    const float* __restrict__ ctx_all, float* __restrict__ out) {
  __shared__ __align__(16) short lsB[2][MAXLEN][LSTRIDE];
  __shared__ float red[8];

  const int t    = threadIdx.x;
  const int w    = t >> 6;      // wave 0..7
  const int lane = t & 63;
  const int qw   = lane >> 4;   // quarter-wave 0..3
  const int lr   = lane & 15;

  const size_t p = blockIdx.x;  // b*64 + k
  const float* ctx = ctx_all + p * (size_t)(2 * MAXLEN * EMB);
  const float* ent = ctx + (size_t)(MAXLEN * EMB);

  // B staging geometry: 8 rounds x (32 rows x 16 float4-cols) covers 256x64
  const int srow = t >> 4;         // 0..31
  const int scol = (t & 15) * 4;   // 0,4,...,60
  const float* gB = ent + (size_t)srow * EMB + scol;

  // A fragment geometry: wave w owns tile-rows 2w, 2w+1 (A rows 32w..32w+31)
  const int lt0 = 2 * w, lt1 = 2 * w + 1;
  const float* gA0 = ctx + (size_t)(lt0 * 16 + lr) * EMB + qw * 8;
  const float* gA1 = ctx + (size_t)(lt1 * 16 + lr) * EMB + qw * 8;

  f32x4 acc[2][16];
#pragma unroll
  for (int h = 0; h < 2; ++h)
#pragma unroll
    for (int mt = 0; mt < 16; ++mt)
      acc[h][mt] = (f32x4){0.f, 0.f, 0.f, 0.f};

  f32x4 rb[8];         // B(s+1) in flight
  f32x4 raA[8];        // A(s+1) in flight: [tile*4 + kh*2 + half]
  bf16x8 afr[2][2];    // A(s) fragments, ready for MFMA

  auto issueB = [&](int s) {
#pragma unroll
    for (int r = 0; r < 8; ++r)
      rb[r] = ntload(gB + (size_t)r * (32 * EMB) + s * BK);
  };
  auto commitB = [&](int buf) {
#pragma unroll
    for (int r = 0; r < 8; ++r) {
      const int row = r * 32 + srow;
      *(uint2*)&lsB[buf][row][scol] = pack4bf(rb[r]);
    }
  };
  auto issueA = [&](int s) {
#pragma unroll
    for (int kh = 0; kh < 2; ++kh)
#pragma unroll
      for (int half = 0; half < 2; ++half) {
        raA[0 * 4 + kh * 2 + half] = ntload(gA0 + s * BK + kh * 32 + half * 4);
        raA[1 * 4 + kh * 2 + half] = ntload(gA1 + s * BK + kh * 32 + half * 4);
      }
  };
  auto packA = [&]() {
#pragma unroll
    for (int tile = 0; tile < 2; ++tile)
#pragma unroll
      for (int kh = 0; kh < 2; ++kh)
        afr[tile][kh] = pack8bf(raA[tile * 4 + kh * 2 + 0], raA[tile * 4 + kh * 2 + 1]);
  };
  auto mfmaStep = [&](int buf) {
#pragma unroll
    for (int kh = 0; kh < 2; ++kh) {
      const int kq = kh * 32 + qw * 8;
#pragma unroll
      for (int mt = 0; mt < 16; ++mt) {
        bf16x8 bfr = __builtin_bit_cast(bf16x8, *(const short8*)&lsB[buf][mt * 16 + lr][kq]);
        acc[0][mt] = __builtin_amdgcn_mfma_f32_16x16x32_bf16(afr[0][kh], bfr, acc[0][mt], 0, 0, 0);
        acc[1][mt] = __builtin_amdgcn_mfma_f32_16x16x32_bf16(afr[1][kh], bfr, acc[1][mt], 0, 0, 0);
      }
    }
  };
  // barrier that does NOT drain vmcnt: global loads stay in flight across it
  auto barrier = [&]() {
    asm volatile("s_waitcnt lgkmcnt(0)" ::: "memory");
    __builtin_amdgcn_sched_barrier(0);
    __builtin_amdgcn_s_barrier();
    __builtin_amdgcn_sched_barrier(0);
  };

  // ---- prologue ----
  issueB(0);        // oldest in flight
  issueA(0);
  commitB(0);       // waits rb (vmcnt(16): A0 stays outstanding)
  issueB(1);
  packA();          // waits raA (vmcnt(16): B1 stays outstanding)
  barrier();

  // ---- steady state: s = 0..9 (full pipeline) ----
  for (int s = 0; s < NSTEP - 2; ++s) {
    issueA(s + 1);            // newest
    commitB((s + 1) & 1);     // waits B(s+1) -> vmcnt keeps A(s+1) in flight
    issueB(s + 2);
    mfmaStep(s & 1);
    packA();                  // waits A(s+1) -> vmcnt keeps B(s+2) in flight
    barrier();                // B(s+2) still outstanding across the barrier
  }
  // ---- peel s = 10 ----
  issueA(NSTEP - 1);
  commitB((NSTEP - 1) & 1);
  mfmaStep((NSTEP - 2) & 1);
  packA();
  barrier();
  // ---- peel s = 11 ----
  mfmaStep((NSTEP - 1) & 1);

  // ---- epilogue: rowmax over m (256 cols), then sum over rows ----
  // C/D layout (16x16x32): col = lane&15, row = (lane>>4)*4 + reg
  float s = 0.f;
#pragma unroll
  for (int h = 0; h < 2; ++h) {
#pragma unroll
    for (int i = 0; i < 4; ++i) {
      float m = acc[h][0][i];
#pragma unroll
      for (int mt = 1; mt < 16; ++mt) m = fmaxf(m, acc[h][mt][i]);
#pragma unroll
      for (int d = 1; d < 16; d <<= 1) m = fmaxf(m, __shfl_xor(m, d, 64));
      s += m;
    }
  }
  s += __shfl_xor(s, 16, 64);
  s += __shfl_xor(s, 32, 64);

  if (lane == 0) red[w] = s;
  __syncthreads();
  if (t == 0) {
    float tot = 0.f;
#pragma unroll
    for (int i = 0; i < 8; ++i) tot += red[i];
    out[p] = tot;
  }
}

extern "C" void kernel_launch(void* const* d_in, const int* in_sizes, int n_in,
                              void* d_out, int out_size, void* d_ws, size_t ws_size,
                              hipStream_t stream) {
  const float* ctx_all = (const float*)d_in[0];
  float* out = (float*)d_out;
  som_rowmax_kernel<<<dim3(512), dim3(512), 0, stream>>>(ctx_all, out);
}